// Round 1
// baseline (63197.321 us; speedup 1.0000x reference)
//
#include <hip/hip_runtime.h>

#define NB    32
#define CIN   64
#define HW    56
#define OHW   57
#define LL    3249          // 57*57
#define PATCH 256
#define NCENT 512
#define PL    (PATCH * LL)  // 831744 per batch
#define NROWS (NB * LL)     // 103968
#define OC    128

#define BR 32
#define BC 32
#define FPAD 260            // 256 + 4, keeps 16B row alignment

// ---------------- c2 = sum(centers^2, axis=1) ----------------
__global__ void c2_kernel(const float* __restrict__ centers, float* __restrict__ c2) {
    int c = blockIdx.x * blockDim.x + threadIdx.x;
    if (c < NCENT) {
        const float4* p = reinterpret_cast<const float4*>(centers + c * PATCH);
        float s = 0.f;
#pragma unroll
        for (int i = 0; i < PATCH / 4; ++i) {
            float4 v = p[i];
            s += v.x * v.x + v.y * v.y + v.z * v.z + v.w * v.w;
        }
        c2[c] = s;
    }
}

// ---------------- fused unfold-gather + cdist-softmax + PV + final ----------------
__global__ __launch_bounds__(256, 2)
void cluster_kernel(const float* __restrict__ x,
                    const float* __restrict__ centers,
                    const float* __restrict__ c2g,
                    const float* __restrict__ temp_p,
                    float* __restrict__ fb) {
    __shared__ float sF[BR][FPAD];
    __shared__ float sC[BC][FPAD];
    __shared__ float sE[BR][BC + 1];
    __shared__ float sX2[BR];
    __shared__ float sC2[BC];
    __shared__ float sDen[BR];

    const int tid = threadIdx.x;
    const float temp = temp_p[0];
    const int n0 = blockIdx.x * BR;

    // ---- gather flat tile: rows n0..n0+31, col q = tid
    for (int r = 0; r < BR; ++r) {
        int n = n0 + r;
        int b = n / LL;
        int rr = n - b * LL;
        int o = rr * PATCH + tid;       // offset in per-batch [P,L] plane
        int p = o / LL;
        int l = o - p * LL;
        int cc = p >> 2;
        int ki = (p >> 1) & 1;
        int kj = p & 1;
        int i = l / OHW;
        int j = l - i * OHW;
        int y = i + ki - 1;
        int xx = j + kj - 1;
        float v = 0.f;
        if ((unsigned)y < HW && (unsigned)xx < HW)
            v = x[((b * CIN + cc) * HW + y) * HW + xx];
        sF[r][tid] = v;
    }
    __syncthreads();

    // ---- x2 per row (8 threads/row, float4 + shfl reduce)
    {
        int r = tid >> 3;
        int s8 = tid & 7;
        float s = 0.f;
#pragma unroll
        for (int m = 0; m < 8; ++m) {
            float4 v = *reinterpret_cast<const float4*>(&sF[r][(s8 + 8 * m) * 4]);
            s += v.x * v.x + v.y * v.y + v.z * v.z + v.w * v.w;
        }
        s += __shfl_xor(s, 1);
        s += __shfl_xor(s, 2);
        s += __shfl_xor(s, 4);
        if (s8 == 0) sX2[r] = s;
    }

    float Tacc[32];
#pragma unroll
    for (int i = 0; i < 32; ++i) Tacc[i] = 0.f;
    float denAcc = 0.f;

    const int ra = tid >> 3;            // row owned for PV/final: 0..31
    const int kg = (tid & 7) * 32;      // k-column group for PV/final
    const int r0 = (tid >> 4) * 2;      // score micro-tile rows
    const int c0 = (tid & 15) * 2;      // score micro-tile centers
    const bool denOwner = ((tid & 7) == 0);

    for (int cb = 0; cb < NCENT / BC; ++cb) {
        __syncthreads();                // protect sC/sE from previous iter readers
        // stage center tile
        const float* cbase = centers + (size_t)(cb * BC) * PATCH;
        for (int r = 0; r < BC; ++r)
            sC[r][tid] = cbase[r * PATCH + tid];
        if (tid < BC) sC2[tid] = c2g[cb * BC + tid];
        __syncthreads();

        // ---- scores: 2x2 micro-tile, float4 k-steps
        float d00 = 0.f, d01 = 0.f, d10 = 0.f, d11 = 0.f;
#pragma unroll 8
        for (int k4 = 0; k4 < PATCH / 4; ++k4) {
            float4 a0 = *reinterpret_cast<const float4*>(&sF[r0][k4 * 4]);
            float4 a1 = *reinterpret_cast<const float4*>(&sF[r0 + 1][k4 * 4]);
            float4 b0 = *reinterpret_cast<const float4*>(&sC[c0][k4 * 4]);
            float4 b1 = *reinterpret_cast<const float4*>(&sC[c0 + 1][k4 * 4]);
            d00 += a0.x * b0.x + a0.y * b0.y + a0.z * b0.z + a0.w * b0.w;
            d01 += a0.x * b1.x + a0.y * b1.y + a0.z * b1.z + a0.w * b1.w;
            d10 += a1.x * b0.x + a1.y * b0.y + a1.z * b0.z + a1.w * b0.w;
            d11 += a1.x * b1.x + a1.y * b1.y + a1.z * b1.z + a1.w * b1.w;
        }
        {
            float x20 = sX2[r0], x21 = sX2[r0 + 1];
            float c20 = sC2[c0], c21 = sC2[c0 + 1];
            float s00 = x20 + c20 - 2.f * d00;
            float s01 = x20 + c21 - 2.f * d01;
            float s10 = x21 + c20 - 2.f * d10;
            float s11 = x21 + c21 - 2.f * d11;
            sE[r0][c0]         = __expf(-temp * sqrtf(fmaxf(s00, 0.f)));
            sE[r0][c0 + 1]     = __expf(-temp * sqrtf(fmaxf(s01, 0.f)));
            sE[r0 + 1][c0]     = __expf(-temp * sqrtf(fmaxf(s10, 0.f)));
            sE[r0 + 1][c0 + 1] = __expf(-temp * sqrtf(fmaxf(s11, 0.f)));
        }
        __syncthreads();

        // ---- PV: Tacc[k] += e[c] * C[c][k]; rotate m to avoid bank conflicts
#pragma unroll 4
        for (int c = 0; c < BC; ++c) {
            float pv = sE[ra][c];
            if (denOwner) denAcc += pv;
#pragma unroll
            for (int m = 0; m < 8; ++m) {
                int mm = (m + ra) & 7;
                float4 cv = *reinterpret_cast<const float4*>(&sC[c][kg + mm * 4]);
                Tacc[mm * 4 + 0] += pv * cv.x;
                Tacc[mm * 4 + 1] += pv * cv.y;
                Tacc[mm * 4 + 2] += pv * cv.z;
                Tacc[mm * 4 + 3] += pv * cv.w;
            }
        }
    }

    if (denOwner) sDen[ra] = denAcc;
    __syncthreads();

    // ---- final = (temp * T/den + flat) / (temp+1), contiguous row chunk write
    {
        float den = sDen[ra];
        float inv = 1.f / (temp + 1.f);
        float tscale = temp / den;
        int n = n0 + ra;
        int b = n / LL;
        int rr = n - b * LL;
        float* dst = fb + (size_t)b * PL + (size_t)rr * PATCH + kg;
#pragma unroll
        for (int m = 0; m < 8; ++m) {
            float4 f = *reinterpret_cast<const float4*>(&sF[ra][kg + m * 4]);
            float4 ov;
            ov.x = (tscale * Tacc[m * 4 + 0] + f.x) * inv;
            ov.y = (tscale * Tacc[m * 4 + 1] + f.y) * inv;
            ov.z = (tscale * Tacc[m * 4 + 2] + f.z) * inv;
            ov.w = (tscale * Tacc[m * 4 + 3] + f.w) * inv;
            *reinterpret_cast<float4*>(dst + m * 4) = ov;
        }
    }
}

// ---------------- fused fold + conv: out[b,:,u,v] = bias + W'[128,256] @ masked final ----------------
__global__ __launch_bounds__(256, 1)
void conv_kernel(const float* __restrict__ fb,
                 const float* __restrict__ weight,
                 const float* __restrict__ bias,
                 float* __restrict__ out) {
    __shared__ float sFt[PATCH][64];    // p x v (57 used, padded to 64)
    __shared__ float sW[OC][68];        // o x p-chunk

    const int tid = threadIdx.x;
    const int u = blockIdx.x;           // 0..56
    const int b = blockIdx.y;           // 0..31

    // stage final columns for this (b,u), applying the fold/conv boundary mask
    const float* src = fb + (size_t)b * PL + (size_t)u * OHW;
    for (int idx = tid; idx < PATCH * OHW; idx += 256) {
        int p = idx / OHW;
        int v = idx - p * OHW;
        int ki = (p >> 1) & 1;
        int kj = p & 1;
        float val = src[p * LL + v];
        bool ok = !((u == 0 && ki == 0) || (u == 56 && ki == 1) ||
                    (v == 0 && kj == 0) || (v == 56 && kj == 1));
        sFt[p][v] = ok ? val : 0.f;
    }
    for (int idx = tid; idx < PATCH * 7; idx += 256) {   // zero pad cols 57..63
        int p = idx / 7;
        sFt[p][57 + (idx - p * 7)] = 0.f;
    }

    const int o0 = (tid >> 3) * 4;      // 4 output channels
    const int vg = tid & 7;             // 8 v's: vg*8 .. vg*8+7
    float acc[4][8];
#pragma unroll
    for (int i = 0; i < 4; ++i)
#pragma unroll
        for (int s = 0; s < 8; ++s) acc[i][s] = 0.f;

    for (int kb = 0; kb < 4; ++kb) {
        __syncthreads();
        for (int idx = tid; idx < OC * 64; idx += 256) {
            int o = idx >> 6;
            int pp = idx & 63;
            sW[o][pp] = weight[o * PATCH + kb * 64 + pp];
        }
        __syncthreads();
#pragma unroll 4
        for (int pp = 0; pp < 64; ++pp) {
            int p = kb * 64 + pp;
            float w0 = sW[o0][pp], w1 = sW[o0 + 1][pp];
            float w2 = sW[o0 + 2][pp], w3 = sW[o0 + 3][pp];
            float4 fa = *reinterpret_cast<const float4*>(&sFt[p][vg * 8]);
            float4 fbv = *reinterpret_cast<const float4*>(&sFt[p][vg * 8 + 4]);
            float f[8] = {fa.x, fa.y, fa.z, fa.w, fbv.x, fbv.y, fbv.z, fbv.w};
#pragma unroll
            for (int s = 0; s < 8; ++s) {
                acc[0][s] += w0 * f[s];
                acc[1][s] += w1 * f[s];
                acc[2][s] += w2 * f[s];
                acc[3][s] += w3 * f[s];
            }
        }
    }

#pragma unroll
    for (int i = 0; i < 4; ++i) {
        int o = o0 + i;
        float bi = bias[o];
        float* dst = out + (((size_t)b * OC + o) * OHW + u) * OHW;
#pragma unroll
        for (int s = 0; s < 8; ++s) {
            int v = vg * 8 + s;
            if (v < OHW) dst[v] = acc[i][s] + bi;
        }
    }
}

extern "C" void kernel_launch(void* const* d_in, const int* in_sizes, int n_in,
                              void* d_out, int out_size, void* d_ws, size_t ws_size,
                              hipStream_t stream) {
    const float* x       = (const float*)d_in[0];
    const float* weight  = (const float*)d_in[1];
    const float* bias    = (const float*)d_in[2];
    const float* centers = (const float*)d_in[3];
    const float* temp    = (const float*)d_in[4];
    float* out = (float*)d_out;

    float* c2 = (float*)d_ws;
    float* fb = (float*)((char*)d_ws + 4096);   // 32*256*3249 floats ≈ 106.5 MB

    c2_kernel<<<2, 256, 0, stream>>>(centers, c2);
    cluster_kernel<<<NROWS / BR, 256, 0, stream>>>(x, centers, c2, temp, fb);
    conv_kernel<<<dim3(OHW, NB), 256, 0, stream>>>(fb, weight, bias, out);
}

// Round 3
// 284.265 us; speedup vs baseline: 222.3184x; 222.3184x over previous
//
#include <hip/hip_runtime.h>
#include <stdint.h>
#include <string.h>

#define NB    32
#define CIN   64
#define HW    56
#define OHW   57
#define LL    3249
#define PATCH 256
#define NCENT 512
#define OC    128
#define NROWS (NB*LL)          // 103968
#define NROWS_PAD 104064       // 813*128
#define PL    (PATCH*LL)       // 831744

typedef __attribute__((ext_vector_type(8))) short short8;      // bf16x8 MFMA frag
typedef __attribute__((ext_vector_type(4))) float f32x4;
typedef __attribute__((ext_vector_type(4))) int   int4v;
typedef int int4u __attribute__((ext_vector_type(4), aligned(4)));
typedef __attribute__((ext_vector_type(4))) unsigned short ushort4v;

// ---------------- ws layout ----------------
constexpr size_t OFF_C2   = 0;
constexpr size_t OFF_X2   = 4096;
constexpr size_t OFF_DEN  = OFF_X2 + (size_t)NROWS_PAD*4;          // 8 partials (nt*2+wc)
constexpr size_t OFF_CBF  = OFF_DEN + (size_t)8*NROWS_PAD*4;
constexpr size_t OFF_CTBF = OFF_CBF + (size_t)NCENT*PATCH*2;
constexpr size_t OFF_WBF  = OFF_CTBF + (size_t)PATCH*NCENT*2;
constexpr size_t OFF_FLAT = OFF_WBF + (size_t)OC*PATCH*2;
constexpr size_t OFF_P    = OFF_FLAT + (size_t)NROWS_PAD*PATCH*2;
constexpr size_t OFF_FBM  = OFF_P + (size_t)NROWS_PAD*NCENT*2;

__device__ __forceinline__ short f2bf(float f) {
    union { float f; uint32_t u; } v; v.f = f;
    uint32_t r = (v.u + 0x7FFFu + ((v.u >> 16) & 1u)) >> 16;
    return (short)r;
}
__device__ __forceinline__ float bf2f(uint16_t h) {
    union { uint32_t u; float f; } v; v.u = ((uint32_t)h) << 16;
    return v.f;
}
__device__ __forceinline__ void gload16(const void* g, void* l) {
    __builtin_amdgcn_global_load_lds(
        (const __attribute__((address_space(1))) unsigned int*)g,
        (__attribute__((address_space(3))) unsigned int*)l, 16, 0, 0);
}

// ---------------- K0a: centers -> cbf (swz), ctbf (T, swz), c2 ----------------
__global__ __launch_bounds__(256)
void k0a_centers(const float* __restrict__ centers, uint16_t* __restrict__ cbf,
                 uint16_t* __restrict__ ctbf, float* __restrict__ c2) {
    __shared__ float red[4];
    int c = blockIdx.x;            // 0..511
    int k = threadIdx.x;           // 0..255
    float v = centers[c*PATCH + k];
    cbf[c*PATCH + (k ^ ((c & 7) << 3))] = (uint16_t)f2bf(v);
    ctbf[k*NCENT + (c ^ ((k & 7) << 3))] = (uint16_t)f2bf(v);
    float s = v*v;
    s += __shfl_xor(s, 1);  s += __shfl_xor(s, 2);  s += __shfl_xor(s, 4);
    s += __shfl_xor(s, 8);  s += __shfl_xor(s, 16); s += __shfl_xor(s, 32);
    int w = threadIdx.x >> 6;
    if ((threadIdx.x & 63) == 0) red[w] = s;
    __syncthreads();
    if (threadIdx.x == 0) c2[c] = red[0] + red[1] + red[2] + red[3];
}

// ---------------- K0w: weight -> wbf (swz) ----------------
__global__ __launch_bounds__(256)
void k0w_weight(const float* __restrict__ weight, uint16_t* __restrict__ wbf) {
    int o = blockIdx.x, p = threadIdx.x;
    wbf[o*PATCH + (p ^ ((o & 7) << 3))] = (uint16_t)f2bf(weight[o*PATCH + p]);
}

// ---------------- K0b: x -> flat bf16 (swz) + x2 ----------------
__global__ __launch_bounds__(256)
void k0b_flat(const float* __restrict__ x, uint16_t* __restrict__ flat,
              float* __restrict__ x2) {
    int tid = threadIdx.x;
    int w = tid >> 6, lane = tid & 63;
    for (int pp = 0; pp < 8; ++pp) {
        int n = blockIdx.x*32 + pp*4 + w;
        int b = n / LL;
        int rr = n - b*LL;
        int k0 = lane*4;
        float s = 0.f;
        ushort4v pk;
#pragma unroll
        for (int e = 0; e < 4; ++e) {
            int k = k0 + e;
            float val = 0.f;
            if (n < NROWS) {
                int o = rr*PATCH + k;
                int p = o / LL; int l = o - p*LL;
                int cc = p >> 2, ki = (p >> 1) & 1, kj = p & 1;
                int i = l / OHW; int j = l - i*OHW;
                int y = i + ki - 1, xx = j + kj - 1;
                if ((unsigned)y < HW && (unsigned)xx < HW)
                    val = x[((b*CIN + cc)*HW + y)*HW + xx];
            }
            pk[e] = (unsigned short)f2bf(val);
            s += val*val;
        }
        *(ushort4v*)(flat + (size_t)n*PATCH + (k0 ^ ((n & 7) << 3))) = pk;
        s += __shfl_xor(s, 1);  s += __shfl_xor(s, 2);  s += __shfl_xor(s, 4);
        s += __shfl_xor(s, 8);  s += __shfl_xor(s, 16); s += __shfl_xor(s, 32);
        if (lane == 0) x2[n] = s;
    }
}

// ---------------- K1: scores GEMM + exp -> P (swz), den partials ----------------
__global__ __launch_bounds__(256, 2)
void k1_scores(const uint16_t* __restrict__ flat, const uint16_t* __restrict__ cbf,
               const float* __restrict__ x2g, const float* __restrict__ c2g,
               const float* __restrict__ temp_p,
               uint16_t* __restrict__ P, float* __restrict__ denp) {
    __shared__ __align__(16) char lds[2][32768];
    const int tid = threadIdx.x;
    const int mt = blockIdx.x, nt = blockIdx.y;
    const int w = tid >> 6, lane = tid & 63;
    const int wr = w >> 1, wc = w & 1;
    const int l15 = lane & 15, l4 = lane >> 4;

    auto stage = [&](int buf, int kt) {
        const char* srcA = (const char*)flat + (size_t)(mt*128)*512 + kt*128;
        const char* srcB = (const char*)cbf + (size_t)(nt*128)*512 + kt*128;
        char* dA = lds[buf];
        char* dB = lds[buf] + 16384;
#pragma unroll
        for (int i = 0; i < 4; ++i) {
            int c = (w*4 + i)*64 + lane;
            gload16(srcA + (size_t)(c >> 3)*512 + (c & 7)*16, dA + (w*4 + i)*1024);
            gload16(srcB + (size_t)(c >> 3)*512 + (c & 7)*16, dB + (w*4 + i)*1024);
        }
    };

    f32x4 acc[4][4];
#pragma unroll
    for (int i = 0; i < 4; ++i)
#pragma unroll
        for (int j = 0; j < 4; ++j) acc[i][j] = (f32x4)0.f;

    stage(0, 0);
    for (int kt = 0; kt < 4; ++kt) {
        __syncthreads();
        if (kt < 3) stage((kt + 1) & 1, kt + 1);
        const char* A = lds[kt & 1];
        const char* B = lds[kt & 1] + 16384;
#pragma unroll
        for (int ks = 0; ks < 2; ++ks) {
            short8 af[4], bfm[4];
#pragma unroll
            for (int rf = 0; rf < 4; ++rf) {
                int row = wr*64 + rf*16 + l15;
                int byte = row*128 + ((ks*64 + l4*16) ^ ((row & 7) << 4));
                af[rf] = *(const short8*)(A + byte);
            }
#pragma unroll
            for (int cf = 0; cf < 4; ++cf) {
                int row = wc*64 + cf*16 + l15;
                int byte = row*128 + ((ks*64 + l4*16) ^ ((row & 7) << 4));
                bfm[cf] = *(const short8*)(B + byte);
            }
#pragma unroll
            for (int rf = 0; rf < 4; ++rf)
#pragma unroll
                for (int cf = 0; cf < 4; ++cf)
                    acc[rf][cf] = __builtin_amdgcn_mfma_f32_16x16x32_bf16(
                        af[rf], bfm[cf], acc[rf][cf], 0, 0, 0);
        }
    }

    // epilogue: exp + den partials
    const float temp = temp_p[0];
    float c2v[4];
#pragma unroll
    for (int cf = 0; cf < 4; ++cf)
        c2v[cf] = c2g[nt*128 + wc*64 + cf*16 + l15];

    float denacc[4][4];
#pragma unroll
    for (int rf = 0; rf < 4; ++rf) {
#pragma unroll
        for (int rr = 0; rr < 4; ++rr) {
            int n = mt*128 + wr*64 + rf*16 + l4*4 + rr;
            float x2v = x2g[n];
            float d = 0.f;
#pragma unroll
            for (int cf = 0; cf < 4; ++cf) {
                float s = x2v + c2v[cf] - 2.f*acc[rf][cf][rr];
                float pv = __expf(-temp * sqrtf(fmaxf(s, 0.f)));
                acc[rf][cf][rr] = pv;
                d += pv;
            }
            denacc[rf][rr] = d;
        }
    }
#pragma unroll
    for (int rf = 0; rf < 4; ++rf)
#pragma unroll
        for (int rr = 0; rr < 4; ++rr) {
            float v = denacc[rf][rr];
            v += __shfl_xor(v, 1); v += __shfl_xor(v, 2);
            v += __shfl_xor(v, 4); v += __shfl_xor(v, 8);
            if (l15 == 0) {
                int n = mt*128 + wr*64 + rf*16 + l4*4 + rr;
                denp[(size_t)(nt*2 + wc)*NROWS_PAD + n] = v;   // FIX: per-wc partial
            }
        }

    // bounce P through LDS (pre-swizzled for K2's staging), then linear store
    __syncthreads();
    uint16_t* Pl = (uint16_t*)lds;
#pragma unroll
    for (int rf = 0; rf < 4; ++rf)
#pragma unroll
        for (int cf = 0; cf < 4; ++cf)
#pragma unroll
            for (int rr = 0; rr < 4; ++rr) {
                int row = wr*64 + rf*16 + l4*4 + rr;
                int cl  = wc*64 + cf*16 + l15;
                Pl[row*128 + (cl ^ ((row & 7) << 3))] = (uint16_t)f2bf(acc[rf][cf][rr]);
            }
    __syncthreads();
#pragma unroll
    for (int i = 0; i < 8; ++i) {
        int c = i*256 + tid;
        int row = c >> 4, sub = c & 15;
        int4v v = *(const int4v*)((const char*)lds + c*16);
        *(int4v*)((char*)P + (size_t)(mt*128 + row)*1024 + nt*256 + sub*16) = v;
    }
}

// ---------------- K2: PV GEMM + final + mask -> fbm bf16 ----------------
__global__ __launch_bounds__(256, 2)
void k2_pv(const uint16_t* __restrict__ P, const uint16_t* __restrict__ ctbf,
           const uint16_t* __restrict__ flat, const float* __restrict__ denp,
           const float* __restrict__ temp_p, uint16_t* __restrict__ fbm) {
    __shared__ __align__(16) char lds[2][32768];
    const int tid = threadIdx.x;
    const int mt = blockIdx.x, nt = blockIdx.y;
    const int w = tid >> 6, lane = tid & 63;
    const int wr = w >> 1, wc = w & 1;
    const int l15 = lane & 15, l4 = lane >> 4;

    auto stage = [&](int buf, int kt) {
        const char* srcA = (const char*)P + (size_t)(mt*128)*1024 + kt*128;
        const char* srcB = (const char*)ctbf + (size_t)(nt*128)*1024 + kt*128;
        char* dA = lds[buf];
        char* dB = lds[buf] + 16384;
#pragma unroll
        for (int i = 0; i < 4; ++i) {
            int c = (w*4 + i)*64 + lane;
            gload16(srcA + (size_t)(c >> 3)*1024 + (c & 7)*16, dA + (w*4 + i)*1024);
            gload16(srcB + (size_t)(c >> 3)*1024 + (c & 7)*16, dB + (w*4 + i)*1024);
        }
    };

    f32x4 acc[4][4];
#pragma unroll
    for (int i = 0; i < 4; ++i)
#pragma unroll
        for (int j = 0; j < 4; ++j) acc[i][j] = (f32x4)0.f;

    stage(0, 0);
    for (int kt = 0; kt < 8; ++kt) {
        __syncthreads();
        if (kt < 7) stage((kt + 1) & 1, kt + 1);
        const char* A = lds[kt & 1];
        const char* B = lds[kt & 1] + 16384;
#pragma unroll
        for (int ks = 0; ks < 2; ++ks) {
            short8 af[4], bfm[4];
#pragma unroll
            for (int rf = 0; rf < 4; ++rf) {
                int row = wr*64 + rf*16 + l15;
                int byte = row*128 + ((ks*64 + l4*16) ^ ((row & 7) << 4));
                af[rf] = *(const short8*)(A + byte);
            }
#pragma unroll
            for (int cf = 0; cf < 4; ++cf) {
                int row = wc*64 + cf*16 + l15;
                int byte = row*128 + ((ks*64 + l4*16) ^ ((row & 7) << 4));
                bfm[cf] = *(const short8*)(B + byte);
            }
#pragma unroll
            for (int rf = 0; rf < 4; ++rf)
#pragma unroll
                for (int cf = 0; cf < 4; ++cf)
                    acc[rf][cf] = __builtin_amdgcn_mfma_f32_16x16x32_bf16(
                        af[rf], bfm[cf], acc[rf][cf], 0, 0, 0);
        }
    }

    const float temp = temp_p[0];
    const float inv = 1.f / (temp + 1.f);
    __syncthreads();
    uint16_t* Fl = (uint16_t*)lds;
#pragma unroll
    for (int rf = 0; rf < 4; ++rf) {
#pragma unroll
        for (int rr = 0; rr < 4; ++rr) {
            int rowl = wr*64 + rf*16 + l4*4 + rr;
            int n = mt*128 + rowl;
            float den = 0.f;
#pragma unroll
            for (int pidx = 0; pidx < 8; ++pidx)
                den += denp[(size_t)pidx*NROWS_PAD + n];       // FIX: sum 8 partials
            float ts = temp / den;
            int rb = n / LL;
            int rrow = n - rb*LL;
#pragma unroll
            for (int cf = 0; cf < 4; ++cf) {
                int cl = wc*64 + cf*16 + l15;
                int m = nt*128 + cl;
                float fl = bf2f(flat[(size_t)n*PATCH + (m ^ ((n & 7) << 3))]);
                float fin = (ts * acc[rf][cf][rr] + fl) * inv;
                int o = rrow*PATCH + m;
                int p = o / LL; int l = o - p*LL;
                int ii = l / OHW; int jj = l - ii*OHW;
                int ki = (p >> 1) & 1, kj = p & 1;
                bool bad = (ii == 0 && ki == 0) || (ii == 56 && ki == 1) ||
                           (jj == 0 && kj == 0) || (jj == 56 && kj == 1);
                Fl[rowl*128 + cl] = (uint16_t)f2bf(bad ? 0.f : fin);
            }
        }
    }
    __syncthreads();
#pragma unroll
    for (int i = 0; i < 8; ++i) {
        int c = i*256 + tid;
        int row = c >> 4, sub = c & 15;
        int n = mt*128 + row;
        if (n < NROWS) {
            int b = n / LL; int r = n - b*LL;
            int4v v = *(const int4v*)((const char*)lds + c*16);
            *(int4v*)((char*)fbm + ((size_t)b*PL + (size_t)r*PATCH + nt*128)*2 + sub*16) = v;
        }
    }
}

// ---------------- K4: conv GEMM: out[oc][l] = W @ fbm^T + bias ----------------
__global__ __launch_bounds__(256, 2)
void k4_conv(const uint16_t* __restrict__ wbf, const uint16_t* __restrict__ fbm,
             const float* __restrict__ bias, float* __restrict__ out) {
    __shared__ __align__(16) char lds[2][32768];
    const int tid = threadIdx.x;
    const int lt = blockIdx.x;     // l-tile 0..25
    const int bb = blockIdx.y;     // batch
    const int w = tid >> 6, lane = tid & 63;
    const int wr = w >> 1, wc = w & 1;
    const int l15 = lane & 15, l4 = lane >> 4;

    auto stageA = [&](int buf, int kt) {
        const char* srcA = (const char*)wbf + kt*128;
        char* dA = lds[buf];
#pragma unroll
        for (int i = 0; i < 4; ++i) {
            int c = (w*4 + i)*64 + lane;
            gload16(srcA + (size_t)(c >> 3)*512 + (c & 7)*16, dA + (w*4 + i)*1024);
        }
    };
    // B: transpose-stage fbm[p][l] -> sB[l][p] (swizzled)
    auto stageB = [&](int buf, int kt) {
        uint16_t* sB = (uint16_t*)(lds[buf] + 16384);
#pragma unroll
        for (int i = 0; i < 4; ++i) {
            int pl = lane;
            int l8 = i*4 + w;
            const uint16_t* g = fbm + (size_t)bb*PL + (size_t)(kt*64 + pl)*LL + lt*128 + l8*8;
#pragma unroll
            for (int e = 0; e < 8; ++e) {
                uint16_t val = g[e];
                int llocal = l8*8 + e;
                sB[llocal*64 + (pl ^ (e << 3))] = val;
            }
        }
    };

    f32x4 acc[4][4];
#pragma unroll
    for (int i = 0; i < 4; ++i)
#pragma unroll
        for (int j = 0; j < 4; ++j) acc[i][j] = (f32x4)0.f;

    stageA(0, 0); stageB(0, 0);
    for (int kt = 0; kt < 4; ++kt) {
        __syncthreads();
        if (kt < 3) { stageA((kt + 1) & 1, kt + 1); stageB((kt + 1) & 1, kt + 1); }
        const char* A = lds[kt & 1];
        const char* B = lds[kt & 1] + 16384;
#pragma unroll
        for (int ks = 0; ks < 2; ++ks) {
            short8 af[4], bfm[4];
#pragma unroll
            for (int rf = 0; rf < 4; ++rf) {
                int row = wr*64 + rf*16 + l15;
                int byte = row*128 + ((ks*64 + l4*16) ^ ((row & 7) << 4));
                af[rf] = *(const short8*)(A + byte);
            }
#pragma unroll
            for (int cf = 0; cf < 4; ++cf) {
                int row = wc*64 + cf*16 + l15;
                int byte = row*128 + ((ks*64 + l4*16) ^ ((row & 7) << 4));
                bfm[cf] = *(const short8*)(B + byte);
            }
#pragma unroll
            for (int rf = 0; rf < 4; ++rf)
#pragma unroll
                for (int cf = 0; cf < 4; ++cf)
                    acc[rf][cf] = __builtin_amdgcn_mfma_f32_16x16x32_bf16(
                        af[rf], bfm[cf], acc[rf][cf], 0, 0, 0);
        }
    }

    __syncthreads();
    float* Ol = (float*)lds;
    float bv[4][4];
#pragma unroll
    for (int rf = 0; rf < 4; ++rf)
#pragma unroll
        for (int rr = 0; rr < 4; ++rr)
            bv[rf][rr] = bias[wr*64 + rf*16 + l4*4 + rr];
#pragma unroll
    for (int rf = 0; rf < 4; ++rf)
#pragma unroll
        for (int cf = 0; cf < 4; ++cf)
#pragma unroll
            for (int rr = 0; rr < 4; ++rr) {
                int row = wr*64 + rf*16 + l4*4 + rr;
                int col = wc*64 + cf*16 + l15;
                Ol[row*128 + col] = acc[rf][cf][rr] + bv[rf][rr];
            }
    __syncthreads();
    if (lt < 25) {
#pragma unroll
        for (int i = 0; i < 16; ++i) {
            int c = i*256 + tid;
            int row = c >> 5, sub = c & 31;
            int4u v = *(const int4u*)((const char*)lds + c*16);
            *(int4u*)((char*)out + ((size_t)(bb*OC + row)*LL + lt*128 + sub*4)*4) = v;
        }
    } else {
#pragma unroll
        for (int i = 0; i < 16; ++i) {
            int c = i*256 + tid;
            int row = c >> 5, sub = c & 31;
            const float* vp = (const float*)((const char*)lds + c*16);
#pragma unroll
            for (int e = 0; e < 4; ++e) {
                int l = lt*128 + sub*4 + e;
                if (l < LL) out[(size_t)(bb*OC + row)*LL + l] = vp[e];
            }
        }
    }
}

extern "C" void kernel_launch(void* const* d_in, const int* in_sizes, int n_in,
                              void* d_out, int out_size, void* d_ws, size_t ws_size,
                              hipStream_t stream) {
    const float* x       = (const float*)d_in[0];
    const float* weight  = (const float*)d_in[1];
    const float* bias    = (const float*)d_in[2];
    const float* centers = (const float*)d_in[3];
    const float* temp    = (const float*)d_in[4];
    float* out = (float*)d_out;

    char* ws = (char*)d_ws;
    float*    c2   = (float*)(ws + OFF_C2);
    float*    x2   = (float*)(ws + OFF_X2);
    float*    den  = (float*)(ws + OFF_DEN);
    uint16_t* cbf  = (uint16_t*)(ws + OFF_CBF);
    uint16_t* ctbf = (uint16_t*)(ws + OFF_CTBF);
    uint16_t* wbf  = (uint16_t*)(ws + OFF_WBF);
    uint16_t* flat = (uint16_t*)(ws + OFF_FLAT);
    uint16_t* P    = (uint16_t*)(ws + OFF_P);
    uint16_t* fbm  = (uint16_t*)(ws + OFF_FBM);

    k0a_centers<<<NCENT, 256, 0, stream>>>(centers, cbf, ctbf, c2);
    k0w_weight<<<OC, 256, 0, stream>>>(weight, wbf);
    k0b_flat<<<NROWS_PAD/32, 256, 0, stream>>>(x, flat, x2);
    k1_scores<<<dim3(NROWS_PAD/128, 4), 256, 0, stream>>>(flat, cbf, x2, c2, temp, P, den);
    k2_pv<<<dim3(NROWS_PAD/128, 2), 256, 0, stream>>>(P, ctbf, flat, den, temp, fbm);
    k4_conv<<<dim3(26, NB), 256, 0, stream>>>(wbf, fbm, bias, out);
}